// Round 1
// baseline (11613.835 us; speedup 1.0000x reference)
//
#include <hip/hip_runtime.h>
#include <math.h>

#define D 512
#define NH 8
#define DH 64
#define NL 6
#define Bsz 4
#define Lseq 1024
#define BL 4096          // B*L tokens
#define Vocab 30000
#define EPS 1e-5f

__device__ __forceinline__ float sigmoidf_(float x) { return 1.0f / (1.0f + expf(-x)); }

// ---------------- embed + pos ----------------
__global__ void embed_kernel(const int* __restrict__ ids, const float* __restrict__ emb,
                             const float* __restrict__ pos, float* __restrict__ x) {
  int tok = blockIdx.x;
  int l = tok & (Lseq - 1);
  int id = ids[tok];
  const float4* e = (const float4*)(emb + (size_t)id * D);
  const float4* p = (const float4*)(pos + (size_t)l * D);
  float4* o = (float4*)(x + (size_t)tok * D);
  float4 a = e[threadIdx.x], b = p[threadIdx.x];
  o[threadIdx.x] = make_float4(a.x + b.x, a.y + b.y, a.z + b.z, a.w + b.w);
}

// ---------------- fused rg gate + modulate + layernorm ----------------
__global__ __launch_bounds__(256) void rg_ln_kernel(
    const float* __restrict__ x, const float* __restrict__ rgw, const float* __restrict__ rgb,
    const float* __restrict__ sc, const float* __restrict__ bi,
    float* __restrict__ h, float* __restrict__ rg_out) {
  __shared__ float red[256];
  int tok = blockIdx.x, t = threadIdx.x;
  const float* xr = x + (size_t)tok * D;
  float x0 = xr[t], x1 = xr[t + 256];
  float rg[4];
#pragma unroll
  for (int g = 0; g < 4; g++) {
    const float* w = rgw + g * D;
    float p = x0 * w[t] + x1 * w[t + 256];
    red[t] = p; __syncthreads();
    for (int s = 128; s > 0; s >>= 1) { if (t < s) red[t] += red[t + s]; __syncthreads(); }
    rg[g] = red[0]; __syncthreads();
  }
  float g0 = sigmoidf_(rg[0] + rgb[0]);
  float g1 = sigmoidf_(rg[1] + rgb[1]);
  float g2 = sigmoidf_(rg[2] + rgb[2]);
  float g3 = sigmoidf_(rg[3] + rgb[3]);
  if (rg_out != nullptr && t == 0) {
    float* ro = rg_out + (size_t)tok * 4;
    ro[0] = g0; ro[1] = g1; ro[2] = g2; ro[3] = g3;
  }
  float mod = 1.0f + 0.25f * (g0 + g1 + g2 + g3);
  float m0 = x0 * mod, m1 = x1 * mod;
  red[t] = m0 + m1; __syncthreads();
  for (int s = 128; s > 0; s >>= 1) { if (t < s) red[t] += red[t + s]; __syncthreads(); }
  float mean = red[0] * (1.0f / D); __syncthreads();
  float d0 = m0 - mean, d1 = m1 - mean;
  red[t] = d0 * d0 + d1 * d1; __syncthreads();
  for (int s = 128; s > 0; s >>= 1) { if (t < s) red[t] += red[t + s]; __syncthreads(); }
  float rstd = rsqrtf(red[0] * (1.0f / D) + EPS);
  h[(size_t)tok * D + t] = d0 * rstd * sc[t] + bi[t];
  h[(size_t)tok * D + t + 256] = d1 * rstd * sc[t + 256] + bi[t + 256];
}

// ---------------- residual + layernorm (in-place into x) ----------------
__global__ __launch_bounds__(256) void residual_ln_kernel(
    float* __restrict__ x, const float* __restrict__ y,
    const float* __restrict__ sc, const float* __restrict__ bi) {
  __shared__ float red[256];
  int tok = blockIdx.x, t = threadIdx.x;
  float v0 = x[(size_t)tok * D + t] + y[(size_t)tok * D + t];
  float v1 = x[(size_t)tok * D + t + 256] + y[(size_t)tok * D + t + 256];
  red[t] = v0 + v1; __syncthreads();
  for (int s = 128; s > 0; s >>= 1) { if (t < s) red[t] += red[t + s]; __syncthreads(); }
  float mean = red[0] * (1.0f / D); __syncthreads();
  float d0 = v0 - mean, d1 = v1 - mean;
  red[t] = d0 * d0 + d1 * d1; __syncthreads();
  for (int s = 128; s > 0; s >>= 1) { if (t < s) red[t] += red[t + s]; __syncthreads(); }
  float rstd = rsqrtf(red[0] * (1.0f / D) + EPS);
  x[(size_t)tok * D + t] = d0 * rstd * sc[t] + bi[t];
  x[(size_t)tok * D + t + 256] = d1 * rstd * sc[t + 256] + bi[t + 256];
}

// ---------------- generic fp32 tiled matmul: C[M,N] = act(A[M,K] @ W[N,K]^T + bias) ----------------
// act: 0=none, 1=gelu(exact), 2=tanh. rowscale: optional per-row scale on A.
__global__ __launch_bounds__(256) void matmul_kernel(
    const float* __restrict__ A, const float* __restrict__ W,
    const float* __restrict__ bias, const float* __restrict__ rowscale,
    float* __restrict__ C, int M, int N, int K, int act) {
  __shared__ float As[16][64];
  __shared__ float Ws[16][64];
  int tid = threadIdx.x;
  int tx = tid & 15, ty = tid >> 4;
  int bn = blockIdx.x * 64, bm = blockIdx.y * 64;
  int lm = tid & 63, lk = (tid >> 6) * 4;
  float c[4][4] = {{0.f}};
  const float* Arow = A + (size_t)(bm + lm) * K;
  float rsl = rowscale ? rowscale[bm + lm] : 1.0f;
  int wn = bn + lm;
  bool wvalid = wn < N;
  const float* Wrow = W + (size_t)(wvalid ? wn : 0) * K;
  for (int k0 = 0; k0 < K; k0 += 16) {
    float4 av = *(const float4*)(Arow + k0 + lk);
    float4 wv = wvalid ? *(const float4*)(Wrow + k0 + lk) : make_float4(0.f, 0.f, 0.f, 0.f);
    __syncthreads();
    As[lk + 0][lm] = av.x * rsl;
    As[lk + 1][lm] = av.y * rsl;
    As[lk + 2][lm] = av.z * rsl;
    As[lk + 3][lm] = av.w * rsl;
    Ws[lk + 0][lm] = wv.x;
    Ws[lk + 1][lm] = wv.y;
    Ws[lk + 2][lm] = wv.z;
    Ws[lk + 3][lm] = wv.w;
    __syncthreads();
#pragma unroll
    for (int kk = 0; kk < 16; kk++) {
      float4 a = *(const float4*)&As[kk][ty * 4];
      float4 w = *(const float4*)&Ws[kk][tx * 4];
      c[0][0] += a.x * w.x; c[0][1] += a.x * w.y; c[0][2] += a.x * w.z; c[0][3] += a.x * w.w;
      c[1][0] += a.y * w.x; c[1][1] += a.y * w.y; c[1][2] += a.y * w.z; c[1][3] += a.y * w.w;
      c[2][0] += a.z * w.x; c[2][1] += a.z * w.y; c[2][2] += a.z * w.z; c[2][3] += a.z * w.w;
      c[3][0] += a.w * w.x; c[3][1] += a.w * w.y; c[3][2] += a.w * w.z; c[3][3] += a.w * w.w;
    }
  }
#pragma unroll
  for (int i = 0; i < 4; i++) {
    int row = bm + ty * 4 + i;
    int col = bn + tx * 4;
    float* crow = C + (size_t)row * N + col;
    float o[4];
#pragma unroll
    for (int j = 0; j < 4; j++) {
      float v = c[i][j] + (bias ? bias[col + j < N ? col + j : 0] : 0.f);
      if (act == 1) v = 0.5f * v * (1.0f + erff(v * 0.7071067811865475f));
      else if (act == 2) v = tanhf(v);
      o[j] = v;
    }
    if (col + 3 < N) {
      *(float4*)crow = make_float4(o[0], o[1], o[2], o[3]);
    } else {
#pragma unroll
      for (int j = 0; j < 4; j++) if (col + j < N) crow[j] = o[j];
    }
  }
}

// ---------------- attention: one block per (b,h, 8-query tile) ----------------
// qkv layout: [B, L, 3, H, DH]; phase: [B*L, H]; out: [B*L, D] (concat heads)
#define TQ 8
__global__ __launch_bounds__(256) void attn_kernel(
    const float* __restrict__ qkv, const float* __restrict__ phase,
    float* __restrict__ out) {
  __shared__ float sS[TQ][Lseq];   // 32 KB
  __shared__ float sQ[TQ][DH];
  __shared__ float sPh[Lseq];
  __shared__ float red[256];
  int bh = blockIdx.y;
  int b = bh >> 3, h = bh & 7;
  int q0 = blockIdx.x * TQ;
  int tid = threadIdx.x;
  for (int j = tid; j < Lseq; j += 256) sPh[j] = phase[((size_t)(b * Lseq + j)) * NH + h];
  for (int idx = tid; idx < TQ * DH; idx += 256) {
    int qi = idx >> 6, d = idx & 63;
    sQ[qi][d] = qkv[(((size_t)(b * Lseq + q0 + qi)) * 3 + 0) * D + h * DH + d];
  }
  __syncthreads();
  // scores = q.k/8 - (ph_i - ph_j)^2
  for (int idx = tid; idx < TQ * Lseq; idx += 256) {
    int qi = idx >> 10, j = idx & (Lseq - 1);
    const float* krow = qkv + (((size_t)(b * Lseq + j)) * 3 + 1) * D + h * DH;
    float acc = 0.f;
#pragma unroll
    for (int d = 0; d < DH; d += 4) {
      float4 k4 = *(const float4*)(krow + d);
      acc += sQ[qi][d] * k4.x + sQ[qi][d + 1] * k4.y + sQ[qi][d + 2] * k4.z + sQ[qi][d + 3] * k4.w;
    }
    float dp = sPh[q0 + qi] - sPh[j];
    sS[qi][j] = acc * 0.125f - dp * dp;
  }
  __syncthreads();
  // softmax per row
  for (int qi = 0; qi < TQ; qi++) {
    float m = -1e30f;
    for (int j = tid; j < Lseq; j += 256) m = fmaxf(m, sS[qi][j]);
    red[tid] = m; __syncthreads();
    for (int s = 128; s > 0; s >>= 1) { if (tid < s) red[tid] = fmaxf(red[tid], red[tid + s]); __syncthreads(); }
    m = red[0]; __syncthreads();
    float sum = 0.f;
    for (int j = tid; j < Lseq; j += 256) { float e = expf(sS[qi][j] - m); sS[qi][j] = e; sum += e; }
    red[tid] = sum; __syncthreads();
    for (int s = 128; s > 0; s >>= 1) { if (tid < s) red[tid] += red[tid + s]; __syncthreads(); }
    float inv = 1.0f / red[0]; __syncthreads();
    for (int j = tid; j < Lseq; j += 256) sS[qi][j] *= inv;
    __syncthreads();
  }
  // PV: wave w handles rows 2w, 2w+1; lane = output dim
  int wv = tid >> 6, lane = tid & 63;
  int r0 = wv * 2, r1 = wv * 2 + 1;
  float acc0 = 0.f, acc1 = 0.f;
  for (int j = 0; j < Lseq; j++) {
    float v = qkv[(((size_t)(b * Lseq + j)) * 3 + 2) * D + h * DH + lane];
    acc0 += sS[r0][j] * v;
    acc1 += sS[r1][j] * v;
  }
  out[((size_t)(b * Lseq + q0 + r0)) * D + h * DH + lane] = acc0;
  out[((size_t)(b * Lseq + q0 + r1)) * D + h * DH + lane] = acc1;
}

// ---------------- boundary gate: sigmoid(dot(tanh_row, w2) + b2) ----------------
__global__ void gate_kernel(const float* __restrict__ tb, const float* __restrict__ w2,
                            const float* __restrict__ b2, float* __restrict__ gate) {
  int tok = blockIdx.x;
  int lane = threadIdx.x;  // 64
  const float* row = tb + (size_t)tok * D;
  float acc = 0.f;
  for (int d = lane; d < D; d += 64) acc += row[d] * w2[d];
  for (int off = 32; off > 0; off >>= 1) acc += __shfl_down(acc, off, 64);
  if (lane == 0) gate[tok] = 1.0f / (1.0f + expf(-(acc + b2[0])));
}

extern "C" void kernel_launch(void* const* d_in, const int* in_sizes, int n_in,
                              void* d_out, int out_size, void* d_ws, size_t ws_size,
                              hipStream_t stream) {
  const int* ids = (const int*)d_in[0];
  const float* emb = (const float*)d_in[1];
  const float* pos = (const float*)d_in[2];
  const float* rg_w = (const float*)d_in[3];
  const float* rg_b = (const float*)d_in[4];
  const float* qkv_w = (const float*)d_in[5];
  const float* qkv_b = (const float*)d_in[6];
  const float* out_w = (const float*)d_in[7];
  const float* out_b = (const float*)d_in[8];
  const float* ph_w = (const float*)d_in[9];
  const float* ph_b = (const float*)d_in[10];
  const float* ff1_w = (const float*)d_in[11];
  const float* ff1_b = (const float*)d_in[12];
  const float* ff2_w = (const float*)d_in[13];
  const float* ff2_b = (const float*)d_in[14];
  const float* n1_s = (const float*)d_in[15];
  const float* n1_b = (const float*)d_in[16];
  const float* n2_s = (const float*)d_in[17];
  const float* n2_b = (const float*)d_in[18];
  const float* bw1 = (const float*)d_in[19];
  const float* bb1 = (const float*)d_in[20];
  const float* bw2 = (const float*)d_in[21];
  const float* bb2 = (const float*)d_in[22];
  const float* head_w = (const float*)d_in[23];

  float* ws = (float*)d_ws;
  float* x     = ws;              // 4096*512  = 2,097,152
  float* hbuf  = ws + 2097152;    // 2,097,152
  float* qkv   = ws + 4194304;    // 4096*1536 = 6,291,456
  float* ao    = ws + 10485760;   // 2,097,152
  float* ff    = ws + 12582912;   // 4096*2048 = 8,388,608
  float* phase = ws + 20971520;   // 4096*8    = 32,768

  float* outf   = (float*)d_out;
  float* logits = outf;                 // 4096*30000
  float* gate   = outf + 122880000;     // 4096
  float* rg_out = outf + 122884096;     // 4096*4

  embed_kernel<<<BL, 128, 0, stream>>>(ids, emb, pos, x);

  for (int l = 0; l < NL; l++) {
    rg_ln_kernel<<<BL, 256, 0, stream>>>(
        x, rg_w + (size_t)l * 4 * D, rg_b + l * 4, n1_s + l * D, n1_b + l * D,
        hbuf, (l == NL - 1) ? rg_out : nullptr);
    matmul_kernel<<<dim3(1536 / 64, BL / 64), 256, 0, stream>>>(
        hbuf, qkv_w + (size_t)l * 1536 * D, qkv_b + l * 1536, nullptr, qkv, BL, 1536, D, 0);
    matmul_kernel<<<dim3(1, BL / 64), 256, 0, stream>>>(
        hbuf, ph_w + (size_t)l * NH * D, ph_b + l * NH, nullptr, phase, BL, NH, D, 0);
    attn_kernel<<<dim3(Lseq / TQ, Bsz * NH), 256, 0, stream>>>(qkv, phase, hbuf);
    matmul_kernel<<<dim3(D / 64, BL / 64), 256, 0, stream>>>(
        hbuf, out_w + (size_t)l * D * D, out_b + l * D, nullptr, ao, BL, D, D, 0);
    residual_ln_kernel<<<BL, 256, 0, stream>>>(x, ao, n1_s + l * D, n1_b + l * D);
    matmul_kernel<<<dim3(2048 / 64, BL / 64), 256, 0, stream>>>(
        x, ff1_w + (size_t)l * 2048 * D, ff1_b + l * 2048, nullptr, ff, BL, 2048, D, 1);
    matmul_kernel<<<dim3(D / 64, BL / 64), 256, 0, stream>>>(
        ff, ff2_w + (size_t)l * D * 2048, ff2_b + l * D, nullptr, ao, BL, D, 2048, 0);
    residual_ln_kernel<<<BL, 256, 0, stream>>>(x, ao, n2_s + l * D, n2_b + l * D);
  }

  matmul_kernel<<<dim3(D / 64, BL / 64), 256, 0, stream>>>(
      x, bw1, bb1, nullptr, ff, BL, D, D, 2);
  gate_kernel<<<BL, 64, 0, stream>>>(ff, bw2, bb2, gate);
  matmul_kernel<<<dim3((Vocab + 63) / 64, BL / 64), 256, 0, stream>>>(
      x, head_w, nullptr, gate, logits, BL, Vocab, D, 0);
}

// Round 2
// 8284.145 us; speedup vs baseline: 1.4019x; 1.4019x over previous
//
#include <hip/hip_runtime.h>
#include <math.h>

#define D 512
#define NH 8
#define DH 64
#define NL 6
#define Bsz 4
#define Lseq 1024
#define BL 4096          // B*L tokens
#define Vocab 30000
#define EPS 1e-5f

typedef __attribute__((ext_vector_type(8))) short s8v;   // 8 bf16 (4 VGPRs)
typedef __attribute__((ext_vector_type(4))) float f32x4; // MFMA accumulator

__device__ __forceinline__ float sigmoidf_(float x) { return 1.0f / (1.0f + expf(-x)); }

__device__ __forceinline__ short f2bf(float f) {  // fp32 -> bf16 bits, RNE
  union { float f; unsigned u; } v; v.f = f;
  return (short)((v.u + 0x7FFFu + ((v.u >> 16) & 1u)) >> 16);
}
__device__ __forceinline__ float bf2f(short s) {
  union { unsigned u; float f; } v; v.u = ((unsigned)(unsigned short)s) << 16;
  return v.f;
}

// ---------------- fp32 -> bf16 bulk convert (weights) ----------------
__global__ void f2bf_kernel(const float* __restrict__ in, short* __restrict__ out, int n) {
  int i = (blockIdx.x * 256 + threadIdx.x) * 8;
  if (i >= n) return;
  float4 a = *(const float4*)(in + i);
  float4 b = *(const float4*)(in + i + 4);
  s8v o;
  o[0] = f2bf(a.x); o[1] = f2bf(a.y); o[2] = f2bf(a.z); o[3] = f2bf(a.w);
  o[4] = f2bf(b.x); o[5] = f2bf(b.y); o[6] = f2bf(b.z); o[7] = f2bf(b.w);
  *(s8v*)(out + i) = o;
}

// ---------------- embed + pos ----------------
__global__ void embed_kernel(const int* __restrict__ ids, const float* __restrict__ emb,
                             const float* __restrict__ pos, float* __restrict__ x) {
  int tok = blockIdx.x;
  int l = tok & (Lseq - 1);
  int id = ids[tok];
  const float4* e = (const float4*)(emb + (size_t)id * D);
  const float4* p = (const float4*)(pos + (size_t)l * D);
  float4* o = (float4*)(x + (size_t)tok * D);
  float4 a = e[threadIdx.x], b = p[threadIdx.x];
  o[threadIdx.x] = make_float4(a.x + b.x, a.y + b.y, a.z + b.z, a.w + b.w);
}

// ---------------- fused rg gate + modulate + layernorm -> bf16 h ----------------
__global__ __launch_bounds__(256) void rg_ln_kernel(
    const float* __restrict__ x, const float* __restrict__ rgw, const float* __restrict__ rgb,
    const float* __restrict__ sc, const float* __restrict__ bi,
    short* __restrict__ h, float* __restrict__ rg_out) {
  __shared__ float red[256];
  int tok = blockIdx.x, t = threadIdx.x;
  const float* xr = x + (size_t)tok * D;
  float x0 = xr[t], x1 = xr[t + 256];
  float rg[4];
#pragma unroll
  for (int g = 0; g < 4; g++) {
    const float* w = rgw + g * D;
    float p = x0 * w[t] + x1 * w[t + 256];
    red[t] = p; __syncthreads();
    for (int s = 128; s > 0; s >>= 1) { if (t < s) red[t] += red[t + s]; __syncthreads(); }
    rg[g] = red[0]; __syncthreads();
  }
  float g0 = sigmoidf_(rg[0] + rgb[0]);
  float g1 = sigmoidf_(rg[1] + rgb[1]);
  float g2 = sigmoidf_(rg[2] + rgb[2]);
  float g3 = sigmoidf_(rg[3] + rgb[3]);
  if (rg_out != nullptr && t == 0) {
    float* ro = rg_out + (size_t)tok * 4;
    ro[0] = g0; ro[1] = g1; ro[2] = g2; ro[3] = g3;
  }
  float mod = 1.0f + 0.25f * (g0 + g1 + g2 + g3);
  float m0 = x0 * mod, m1 = x1 * mod;
  red[t] = m0 + m1; __syncthreads();
  for (int s = 128; s > 0; s >>= 1) { if (t < s) red[t] += red[t + s]; __syncthreads(); }
  float mean = red[0] * (1.0f / D); __syncthreads();
  float d0 = m0 - mean, d1 = m1 - mean;
  red[t] = d0 * d0 + d1 * d1; __syncthreads();
  for (int s = 128; s > 0; s >>= 1) { if (t < s) red[t] += red[t + s]; __syncthreads(); }
  float rstd = rsqrtf(red[0] * (1.0f / D) + EPS);
  h[(size_t)tok * D + t] = f2bf(d0 * rstd * sc[t] + bi[t]);
  h[(size_t)tok * D + t + 256] = f2bf(d1 * rstd * sc[t + 256] + bi[t + 256]);
}

// ---------------- residual + layernorm (in-place into x) + bf16 copy ----------------
__global__ __launch_bounds__(256) void residual_ln_kernel(
    float* __restrict__ x, const float* __restrict__ y,
    const float* __restrict__ sc, const float* __restrict__ bi,
    short* __restrict__ xb) {
  __shared__ float red[256];
  int tok = blockIdx.x, t = threadIdx.x;
  float v0 = x[(size_t)tok * D + t] + y[(size_t)tok * D + t];
  float v1 = x[(size_t)tok * D + t + 256] + y[(size_t)tok * D + t + 256];
  red[t] = v0 + v1; __syncthreads();
  for (int s = 128; s > 0; s >>= 1) { if (t < s) red[t] += red[t + s]; __syncthreads(); }
  float mean = red[0] * (1.0f / D); __syncthreads();
  float d0 = v0 - mean, d1 = v1 - mean;
  red[t] = d0 * d0 + d1 * d1; __syncthreads();
  for (int s = 128; s > 0; s >>= 1) { if (t < s) red[t] += red[t + s]; __syncthreads(); }
  float rstd = rsqrtf(red[0] * (1.0f / D) + EPS);
  float o0 = d0 * rstd * sc[t] + bi[t];
  float o1 = d1 * rstd * sc[t + 256] + bi[t + 256];
  x[(size_t)tok * D + t] = o0;
  x[(size_t)tok * D + t + 256] = o1;
  xb[(size_t)tok * D + t] = f2bf(o0);
  xb[(size_t)tok * D + t + 256] = f2bf(o1);
}

// ---------------- bf16 MFMA GEMM: C[M,N] = act(A[M,K] @ W[N,K]^T + bias) ----------------
// A: bf16. W: bf16 (CONVW=false) or fp32 converted in staging (CONVW=true).
// OUTBF: write bf16 to Cb instead of fp32 to C. act: 0=none, 1=gelu exact, 2=tanh.
template <bool CONVW, bool OUTBF>
__global__ __launch_bounds__(256) void gemm_kernel(
    const short* __restrict__ A, const void* __restrict__ Wp,
    const float* __restrict__ bias, float* __restrict__ C, short* __restrict__ Cb,
    int M, int N, int K, int act) {
  __shared__ short As[128][32];
  __shared__ short Ws[128][32];
  int tid = threadIdx.x;
  int bn = blockIdx.x * 128, bm = blockIdx.y * 128;
  int wid = tid >> 6, lane = tid & 63;
  int wm = (wid >> 1) * 64, wn = (wid & 1) * 64;
  int fr = lane & 15, kg = lane >> 4;
  f32x4 acc[4][4] = {};
  int sr = tid >> 1;            // staged row within tile
  int sc = (tid & 1) * 16;      // staged col (elements)
  const short* Arow = A + (size_t)(bm + sr) * K + sc;
  int wrow = bn + sr;
  int wclamp = wrow < N ? wrow : 0;
  const short* Wrow_b = CONVW ? nullptr : (const short*)Wp + (size_t)wclamp * K + sc;
  const float* Wrow_f = CONVW ? (const float*)Wp + (size_t)wclamp * K + sc : nullptr;
  for (int k0 = 0; k0 < K; k0 += 32) {
    s8v a0 = *(const s8v*)(Arow + k0);
    s8v a1 = *(const s8v*)(Arow + k0 + 8);
    s8v w0, w1;
    if (CONVW) {
      float4 f0 = *(const float4*)(Wrow_f + k0);
      float4 f1 = *(const float4*)(Wrow_f + k0 + 4);
      float4 f2 = *(const float4*)(Wrow_f + k0 + 8);
      float4 f3 = *(const float4*)(Wrow_f + k0 + 12);
      w0[0] = f2bf(f0.x); w0[1] = f2bf(f0.y); w0[2] = f2bf(f0.z); w0[3] = f2bf(f0.w);
      w0[4] = f2bf(f1.x); w0[5] = f2bf(f1.y); w0[6] = f2bf(f1.z); w0[7] = f2bf(f1.w);
      w1[0] = f2bf(f2.x); w1[1] = f2bf(f2.y); w1[2] = f2bf(f2.z); w1[3] = f2bf(f2.w);
      w1[4] = f2bf(f3.x); w1[5] = f2bf(f3.y); w1[6] = f2bf(f3.z); w1[7] = f2bf(f3.w);
    } else {
      w0 = *(const s8v*)(Wrow_b + k0);
      w1 = *(const s8v*)(Wrow_b + k0 + 8);
    }
    __syncthreads();
    *(s8v*)&As[sr][sc] = a0;
    *(s8v*)&As[sr][sc + 8] = a1;
    *(s8v*)&Ws[sr][sc] = w0;
    *(s8v*)&Ws[sr][sc + 8] = w1;
    __syncthreads();
    s8v af[4], bf[4];
#pragma unroll
    for (int m = 0; m < 4; m++) af[m] = *(const s8v*)&As[wm + m * 16 + fr][kg * 8];
#pragma unroll
    for (int n = 0; n < 4; n++) bf[n] = *(const s8v*)&Ws[wn + n * 16 + fr][kg * 8];
#pragma unroll
    for (int m = 0; m < 4; m++)
#pragma unroll
      for (int n = 0; n < 4; n++)
        acc[m][n] = __builtin_amdgcn_mfma_f32_16x16x32_bf16(af[m], bf[n], acc[m][n], 0, 0, 0);
  }
  // epilogue: C/D layout col=lane&15, row=(lane>>4)*4+reg
  int rbase = bm + wm + (lane >> 4) * 4;
#pragma unroll
  for (int n = 0; n < 4; n++) {
    int col = bn + wn + n * 16 + (lane & 15);
    if (col >= N) continue;
    float bv = bias ? bias[col] : 0.0f;
#pragma unroll
    for (int m = 0; m < 4; m++) {
#pragma unroll
      for (int r = 0; r < 4; r++) {
        int row = rbase + m * 16 + r;
        float v = acc[m][n][r] + bv;
        if (act == 1) v = 0.5f * v * (1.0f + erff(v * 0.7071067811865475f));
        else if (act == 2) v = tanhf(v);
        if (OUTBF) Cb[(size_t)row * N + col] = f2bf(v);
        else C[(size_t)row * N + col] = v;
      }
    }
  }
}

// ---------------- phase: phase[tok][h] = h_bf[tok] . pw[h] + pb[h] ----------------
__global__ __launch_bounds__(256) void phase_kernel(
    const short* __restrict__ hbf, const float* __restrict__ pw,
    const float* __restrict__ pb, float* __restrict__ phase) {
  int tok = blockIdx.x, t = threadIdx.x;
  int h = t >> 5, ln = t & 31;
  const short* hr = hbf + (size_t)tok * D;
  const s8v* hv = (const s8v*)(hr + ln * 16);
  s8v h0 = hv[0], h1 = hv[1];
  const float4* wv = (const float4*)(pw + (size_t)h * D + ln * 16);
  float4 w0 = wv[0], w1 = wv[1], w2 = wv[2], w3 = wv[3];
  float acc = 0.f;
  acc += bf2f(h0[0]) * w0.x + bf2f(h0[1]) * w0.y + bf2f(h0[2]) * w0.z + bf2f(h0[3]) * w0.w;
  acc += bf2f(h0[4]) * w1.x + bf2f(h0[5]) * w1.y + bf2f(h0[6]) * w1.z + bf2f(h0[7]) * w1.w;
  acc += bf2f(h1[0]) * w2.x + bf2f(h1[1]) * w2.y + bf2f(h1[2]) * w2.z + bf2f(h1[3]) * w2.w;
  acc += bf2f(h1[4]) * w3.x + bf2f(h1[5]) * w3.y + bf2f(h1[6]) * w3.z + bf2f(h1[7]) * w3.w;
  for (int off = 16; off > 0; off >>= 1) acc += __shfl_down(acc, off, 32);
  if (ln == 0) phase[(size_t)tok * NH + h] = acc + pb[h];
}

// ---------------- attention (fp32), writes bf16 ----------------
#define TQ 8
__global__ __launch_bounds__(256) void attn_kernel(
    const float* __restrict__ qkv, const float* __restrict__ phase,
    short* __restrict__ out) {
  __shared__ float sS[TQ][Lseq];   // 32 KB
  __shared__ float sQ[TQ][DH];
  __shared__ float sPh[Lseq];
  __shared__ float red[256];
  int bh = blockIdx.y;
  int b = bh >> 3, h = bh & 7;
  int q0 = blockIdx.x * TQ;
  int tid = threadIdx.x;
  for (int j = tid; j < Lseq; j += 256) sPh[j] = phase[((size_t)(b * Lseq + j)) * NH + h];
  for (int idx = tid; idx < TQ * DH; idx += 256) {
    int qi = idx >> 6, d = idx & 63;
    sQ[qi][d] = qkv[(((size_t)(b * Lseq + q0 + qi)) * 3 + 0) * D + h * DH + d];
  }
  __syncthreads();
  for (int idx = tid; idx < TQ * Lseq; idx += 256) {
    int qi = idx >> 10, j = idx & (Lseq - 1);
    const float* krow = qkv + (((size_t)(b * Lseq + j)) * 3 + 1) * D + h * DH;
    float acc = 0.f;
#pragma unroll
    for (int d = 0; d < DH; d += 4) {
      float4 k4 = *(const float4*)(krow + d);
      acc += sQ[qi][d] * k4.x + sQ[qi][d + 1] * k4.y + sQ[qi][d + 2] * k4.z + sQ[qi][d + 3] * k4.w;
    }
    float dp = sPh[q0 + qi] - sPh[j];
    sS[qi][j] = acc * 0.125f - dp * dp;
  }
  __syncthreads();
  for (int qi = 0; qi < TQ; qi++) {
    float m = -1e30f;
    for (int j = tid; j < Lseq; j += 256) m = fmaxf(m, sS[qi][j]);
    red[tid] = m; __syncthreads();
    for (int s = 128; s > 0; s >>= 1) { if (tid < s) red[tid] = fmaxf(red[tid], red[tid + s]); __syncthreads(); }
    m = red[0]; __syncthreads();
    float sum = 0.f;
    for (int j = tid; j < Lseq; j += 256) { float e = expf(sS[qi][j] - m); sS[qi][j] = e; sum += e; }
    red[tid] = sum; __syncthreads();
    for (int s = 128; s > 0; s >>= 1) { if (tid < s) red[tid] += red[tid + s]; __syncthreads(); }
    float inv = 1.0f / red[0]; __syncthreads();
    for (int j = tid; j < Lseq; j += 256) sS[qi][j] *= inv;
    __syncthreads();
  }
  int wv = tid >> 6, lane = tid & 63;
  int r0 = wv * 2, r1 = wv * 2 + 1;
  float acc0 = 0.f, acc1 = 0.f;
  for (int j = 0; j < Lseq; j++) {
    float v = qkv[(((size_t)(b * Lseq + j)) * 3 + 2) * D + h * DH + lane];
    acc0 += sS[r0][j] * v;
    acc1 += sS[r1][j] * v;
  }
  out[((size_t)(b * Lseq + q0 + r0)) * D + h * DH + lane] = f2bf(acc0);
  out[((size_t)(b * Lseq + q0 + r1)) * D + h * DH + lane] = f2bf(acc1);
}

// ---------------- boundary gate ----------------
__global__ void gate_kernel(const float* __restrict__ tb, const float* __restrict__ w2,
                            const float* __restrict__ b2, float* __restrict__ gate) {
  int tok = blockIdx.x;
  int lane = threadIdx.x;  // 64
  const float* row = tb + (size_t)tok * D;
  float acc = 0.f;
  for (int d = lane; d < D; d += 64) acc += row[d] * w2[d];
  for (int off = 32; off > 0; off >>= 1) acc += __shfl_down(acc, off, 64);
  if (lane == 0) gate[tok] = 1.0f / (1.0f + expf(-(acc + b2[0])));
}

// ---------------- xg = bf16(x * gate) ----------------
__global__ void xg_kernel(const float* __restrict__ x, const float* __restrict__ gate,
                          short* __restrict__ xg) {
  int tok = blockIdx.x, t = threadIdx.x;  // 128 threads x 4 elems
  float g = gate[tok];
  float4 v = *(const float4*)(x + (size_t)tok * D + t * 4);
  short4 o = make_short4(f2bf(v.x * g), f2bf(v.y * g), f2bf(v.z * g), f2bf(v.w * g));
  *(short4*)(xg + (size_t)tok * D + t * 4) = o;
}

extern "C" void kernel_launch(void* const* d_in, const int* in_sizes, int n_in,
                              void* d_out, int out_size, void* d_ws, size_t ws_size,
                              hipStream_t stream) {
  const int* ids = (const int*)d_in[0];
  const float* emb = (const float*)d_in[1];
  const float* pos = (const float*)d_in[2];
  const float* rg_w = (const float*)d_in[3];
  const float* rg_b = (const float*)d_in[4];
  const float* qkv_w = (const float*)d_in[5];
  const float* qkv_b = (const float*)d_in[6];
  const float* out_w = (const float*)d_in[7];
  const float* out_b = (const float*)d_in[8];
  const float* ph_w = (const float*)d_in[9];
  const float* ph_b = (const float*)d_in[10];
  const float* ff1_w = (const float*)d_in[11];
  const float* ff1_b = (const float*)d_in[12];
  const float* ff2_w = (const float*)d_in[13];
  const float* ff2_b = (const float*)d_in[14];
  const float* n1_s = (const float*)d_in[15];
  const float* n1_b = (const float*)d_in[16];
  const float* n2_s = (const float*)d_in[17];
  const float* n2_b = (const float*)d_in[18];
  const float* bw1 = (const float*)d_in[19];
  const float* bb1 = (const float*)d_in[20];
  const float* bw2 = (const float*)d_in[21];
  const float* bb2 = (const float*)d_in[22];
  const float* head_w = (const float*)d_in[23];

  char* w = (char*)d_ws;
  // fp32 region
  float* x     = (float*)(w + 0);           //  8.39 MB
  float* qkvb  = (float*)(w + 8388608);     // 25.17 MB (reused as tanh-buf tb after loop)
  float* ao    = (float*)(w + 33554432);    //  8.39 MB
  float* phase = (float*)(w + 41943040);    //  0.13 MB
  // bf16 activations
  short* h_bf  = (short*)(w + 41975808);    //  4.19 MB
  short* ao_bf = (short*)(w + 46170112);    //  4.19 MB
  short* x_bf  = (short*)(w + 50364416);    //  4.19 MB
  short* ff_bf = (short*)(w + 54558720);    // 16.78 MB
  short* xg_bf = (short*)(w + 71335936);    //  4.19 MB
  // bf16 weights (optional fast path)
  short* wqkv  = (short*)(w + 75530240);    //  9.44 MB
  short* wout  = (short*)(w + 84967424);    //  3.15 MB
  short* wff1  = (short*)(w + 88113152);    // 12.58 MB
  short* wff2  = (short*)(w + 100696064);   // 12.58 MB
  short* wbnd  = (short*)(w + 113278976);   //  0.52 MB
  short* whead = (short*)(w + 113803264);   // 30.72 MB
  const size_t WS_FULL = 144523264;

  float* outf   = (float*)d_out;
  float* logits = outf;
  float* gate   = outf + 122880000;
  float* rg_out = outf + 122884096;

  bool fast = ws_size >= WS_FULL;

  if (fast) {
    f2bf_kernel<<<(4718592 / 8 + 255) / 256, 256, 0, stream>>>(qkv_w, wqkv, 4718592);
    f2bf_kernel<<<(1572864 / 8 + 255) / 256, 256, 0, stream>>>(out_w, wout, 1572864);
    f2bf_kernel<<<(6291456 / 8 + 255) / 256, 256, 0, stream>>>(ff1_w, wff1, 6291456);
    f2bf_kernel<<<(6291456 / 8 + 255) / 256, 256, 0, stream>>>(ff2_w, wff2, 6291456);
    f2bf_kernel<<<(262144 / 8 + 255) / 256, 256, 0, stream>>>(bw1, wbnd, 262144);
    f2bf_kernel<<<(15360000 / 8 + 255) / 256, 256, 0, stream>>>(head_w, whead, 15360000);
  }

  embed_kernel<<<BL, 128, 0, stream>>>(ids, emb, pos, x);

  for (int l = 0; l < NL; l++) {
    rg_ln_kernel<<<BL, 256, 0, stream>>>(
        x, rg_w + (size_t)l * 4 * D, rg_b + l * 4, n1_s + l * D, n1_b + l * D,
        h_bf, (l == NL - 1) ? rg_out : nullptr);
    if (fast)
      gemm_kernel<false, false><<<dim3(12, 32), 256, 0, stream>>>(
          h_bf, wqkv + (size_t)l * 1536 * D, qkv_b + l * 1536, qkvb, nullptr, BL, 1536, D, 0);
    else
      gemm_kernel<true, false><<<dim3(12, 32), 256, 0, stream>>>(
          h_bf, qkv_w + (size_t)l * 1536 * D, qkv_b + l * 1536, qkvb, nullptr, BL, 1536, D, 0);
    phase_kernel<<<BL, 256, 0, stream>>>(h_bf, ph_w + (size_t)l * NH * D, ph_b + l * NH, phase);
    attn_kernel<<<dim3(Lseq / TQ, Bsz * NH), 256, 0, stream>>>(qkvb, phase, ao_bf);
    if (fast)
      gemm_kernel<false, false><<<dim3(4, 32), 256, 0, stream>>>(
          ao_bf, wout + (size_t)l * D * D, out_b + l * D, ao, nullptr, BL, D, D, 0);
    else
      gemm_kernel<true, false><<<dim3(4, 32), 256, 0, stream>>>(
          ao_bf, out_w + (size_t)l * D * D, out_b + l * D, ao, nullptr, BL, D, D, 0);
    residual_ln_kernel<<<BL, 256, 0, stream>>>(x, ao, n1_s + l * D, n1_b + l * D, x_bf);
    if (fast)
      gemm_kernel<false, true><<<dim3(16, 32), 256, 0, stream>>>(
          x_bf, wff1 + (size_t)l * 2048 * D, ff1_b + l * 2048, nullptr, ff_bf, BL, 2048, D, 1);
    else
      gemm_kernel<true, true><<<dim3(16, 32), 256, 0, stream>>>(
          x_bf, ff1_w + (size_t)l * 2048 * D, ff1_b + l * 2048, nullptr, ff_bf, BL, 2048, D, 1);
    if (fast)
      gemm_kernel<false, false><<<dim3(4, 32), 256, 0, stream>>>(
          ff_bf, wff2 + (size_t)l * D * 2048, ff2_b + l * D, ao, nullptr, BL, D, 2048, 0);
    else
      gemm_kernel<true, false><<<dim3(4, 32), 256, 0, stream>>>(
          ff_bf, ff2_w + (size_t)l * D * 2048, ff2_b + l * D, ao, nullptr, BL, D, 2048, 0);
    residual_ln_kernel<<<BL, 256, 0, stream>>>(x, ao, n2_s + l * D, n2_b + l * D, x_bf);
  }

  if (fast)
    gemm_kernel<false, false><<<dim3(4, 32), 256, 0, stream>>>(
        x_bf, wbnd, bb1, qkvb, nullptr, BL, D, D, 2);
  else
    gemm_kernel<true, false><<<dim3(4, 32), 256, 0, stream>>>(
        x_bf, bw1, bb1, qkvb, nullptr, BL, D, D, 2);
  gate_kernel<<<BL, 64, 0, stream>>>(qkvb, bw2, bb2, gate);
  xg_kernel<<<BL, 128, 0, stream>>>(x, gate, xg_bf);
  if (fast)
    gemm_kernel<false, false><<<dim3(235, 32), 256, 0, stream>>>(
        xg_bf, whead, nullptr, logits, nullptr, BL, Vocab, D, 0);
  else
    gemm_kernel<true, false><<<dim3(235, 32), 256, 0, stream>>>(
        xg_bf, head_w, nullptr, logits, nullptr, BL, Vocab, D, 0);
}

// Round 3
// 1753.640 us; speedup vs baseline: 6.6227x; 4.7240x over previous
//
#include <hip/hip_runtime.h>
#include <math.h>

#define D 512
#define NH 8
#define DH 64
#define NL 6
#define Bsz 4
#define Lseq 1024
#define BL 4096          // B*L tokens
#define Vocab 30000
#define EPS 1e-5f

typedef __attribute__((ext_vector_type(8))) short s8v;   // 8 bf16 (4 VGPRs)
typedef __attribute__((ext_vector_type(4))) float f32x4; // MFMA accumulator

__device__ __forceinline__ float sigmoidf_(float x) { return 1.0f / (1.0f + expf(-x)); }

__device__ __forceinline__ short f2bf(float f) {  // fp32 -> bf16 bits, RNE
  union { float f; unsigned u; } v; v.f = f;
  return (short)((v.u + 0x7FFFu + ((v.u >> 16) & 1u)) >> 16);
}
__device__ __forceinline__ float bf2f(short s) {
  union { unsigned u; float f; } v; v.u = ((unsigned)(unsigned short)s) << 16;
  return v.f;
}

// ---------------- fp32 -> bf16 bulk convert (weights) ----------------
__global__ void f2bf_kernel(const float* __restrict__ in, short* __restrict__ out, int n) {
  int i = (blockIdx.x * 256 + threadIdx.x) * 8;
  if (i >= n) return;
  float4 a = *(const float4*)(in + i);
  float4 b = *(const float4*)(in + i + 4);
  s8v o;
  o[0] = f2bf(a.x); o[1] = f2bf(a.y); o[2] = f2bf(a.z); o[3] = f2bf(a.w);
  o[4] = f2bf(b.x); o[5] = f2bf(b.y); o[6] = f2bf(b.z); o[7] = f2bf(b.w);
  *(s8v*)(out + i) = o;
}

// ---------------- embed + pos ----------------
__global__ void embed_kernel(const int* __restrict__ ids, const float* __restrict__ emb,
                             const float* __restrict__ pos, float* __restrict__ x) {
  int tok = blockIdx.x;
  int l = tok & (Lseq - 1);
  int id = ids[tok];
  const float4* e = (const float4*)(emb + (size_t)id * D);
  const float4* p = (const float4*)(pos + (size_t)l * D);
  float4* o = (float4*)(x + (size_t)tok * D);
  float4 a = e[threadIdx.x], b = p[threadIdx.x];
  o[threadIdx.x] = make_float4(a.x + b.x, a.y + b.y, a.z + b.z, a.w + b.w);
}

// ---------------- fused rg gate + modulate + layernorm -> bf16 h ----------------
__global__ __launch_bounds__(256) void rg_ln_kernel(
    const float* __restrict__ x, const float* __restrict__ rgw, const float* __restrict__ rgb,
    const float* __restrict__ sc, const float* __restrict__ bi,
    short* __restrict__ h, float* __restrict__ rg_out) {
  __shared__ float red[256];
  int tok = blockIdx.x, t = threadIdx.x;
  const float* xr = x + (size_t)tok * D;
  float x0 = xr[t], x1 = xr[t + 256];
  float rg[4];
#pragma unroll
  for (int g = 0; g < 4; g++) {
    const float* w = rgw + g * D;
    float p = x0 * w[t] + x1 * w[t + 256];
    red[t] = p; __syncthreads();
    for (int s = 128; s > 0; s >>= 1) { if (t < s) red[t] += red[t + s]; __syncthreads(); }
    rg[g] = red[0]; __syncthreads();
  }
  float g0 = sigmoidf_(rg[0] + rgb[0]);
  float g1 = sigmoidf_(rg[1] + rgb[1]);
  float g2 = sigmoidf_(rg[2] + rgb[2]);
  float g3 = sigmoidf_(rg[3] + rgb[3]);
  if (rg_out != nullptr && t == 0) {
    float* ro = rg_out + (size_t)tok * 4;
    ro[0] = g0; ro[1] = g1; ro[2] = g2; ro[3] = g3;
  }
  float mod = 1.0f + 0.25f * (g0 + g1 + g2 + g3);
  float m0 = x0 * mod, m1 = x1 * mod;
  red[t] = m0 + m1; __syncthreads();
  for (int s = 128; s > 0; s >>= 1) { if (t < s) red[t] += red[t + s]; __syncthreads(); }
  float mean = red[0] * (1.0f / D); __syncthreads();
  float d0 = m0 - mean, d1 = m1 - mean;
  red[t] = d0 * d0 + d1 * d1; __syncthreads();
  for (int s = 128; s > 0; s >>= 1) { if (t < s) red[t] += red[t + s]; __syncthreads(); }
  float rstd = rsqrtf(red[0] * (1.0f / D) + EPS);
  h[(size_t)tok * D + t] = f2bf(d0 * rstd * sc[t] + bi[t]);
  h[(size_t)tok * D + t + 256] = f2bf(d1 * rstd * sc[t + 256] + bi[t + 256]);
}

// ---------------- residual + layernorm (in-place into x) + bf16 copy ----------------
__global__ __launch_bounds__(256) void residual_ln_kernel(
    float* __restrict__ x, const float* __restrict__ y,
    const float* __restrict__ sc, const float* __restrict__ bi,
    short* __restrict__ xb) {
  __shared__ float red[256];
  int tok = blockIdx.x, t = threadIdx.x;
  float v0 = x[(size_t)tok * D + t] + y[(size_t)tok * D + t];
  float v1 = x[(size_t)tok * D + t + 256] + y[(size_t)tok * D + t + 256];
  red[t] = v0 + v1; __syncthreads();
  for (int s = 128; s > 0; s >>= 1) { if (t < s) red[t] += red[t + s]; __syncthreads(); }
  float mean = red[0] * (1.0f / D); __syncthreads();
  float d0 = v0 - mean, d1 = v1 - mean;
  red[t] = d0 * d0 + d1 * d1; __syncthreads();
  for (int s = 128; s > 0; s >>= 1) { if (t < s) red[t] += red[t + s]; __syncthreads(); }
  float rstd = rsqrtf(red[0] * (1.0f / D) + EPS);
  float o0 = d0 * rstd * sc[t] + bi[t];
  float o1 = d1 * rstd * sc[t + 256] + bi[t + 256];
  x[(size_t)tok * D + t] = o0;
  x[(size_t)tok * D + t + 256] = o1;
  xb[(size_t)tok * D + t] = f2bf(o0);
  xb[(size_t)tok * D + t + 256] = f2bf(o1);
}

// ---------------- bf16 MFMA GEMM: C[M,N] = act(A[M,K] @ W[N,K]^T + bias) ----------------
template <bool CONVW, bool OUTBF>
__global__ __launch_bounds__(256) void gemm_kernel(
    const short* __restrict__ A, const void* __restrict__ Wp,
    const float* __restrict__ bias, float* __restrict__ C, short* __restrict__ Cb,
    int M, int N, int K, int act) {
  __shared__ short As[128][32];
  __shared__ short Ws[128][32];
  int tid = threadIdx.x;
  int bn = blockIdx.x * 128, bm = blockIdx.y * 128;
  int wid = tid >> 6, lane = tid & 63;
  int wm = (wid >> 1) * 64, wn = (wid & 1) * 64;
  int fr = lane & 15, kg = lane >> 4;
  f32x4 acc[4][4] = {};
  int sr = tid >> 1;
  int sc = (tid & 1) * 16;
  const short* Arow = A + (size_t)(bm + sr) * K + sc;
  int wrow = bn + sr;
  int wclamp = wrow < N ? wrow : 0;
  const short* Wrow_b = CONVW ? nullptr : (const short*)Wp + (size_t)wclamp * K + sc;
  const float* Wrow_f = CONVW ? (const float*)Wp + (size_t)wclamp * K + sc : nullptr;
  for (int k0 = 0; k0 < K; k0 += 32) {
    s8v a0 = *(const s8v*)(Arow + k0);
    s8v a1 = *(const s8v*)(Arow + k0 + 8);
    s8v w0, w1;
    if (CONVW) {
      float4 f0 = *(const float4*)(Wrow_f + k0);
      float4 f1 = *(const float4*)(Wrow_f + k0 + 4);
      float4 f2 = *(const float4*)(Wrow_f + k0 + 8);
      float4 f3 = *(const float4*)(Wrow_f + k0 + 12);
      w0[0] = f2bf(f0.x); w0[1] = f2bf(f0.y); w0[2] = f2bf(f0.z); w0[3] = f2bf(f0.w);
      w0[4] = f2bf(f1.x); w0[5] = f2bf(f1.y); w0[6] = f2bf(f1.z); w0[7] = f2bf(f1.w);
      w1[0] = f2bf(f2.x); w1[1] = f2bf(f2.y); w1[2] = f2bf(f2.z); w1[3] = f2bf(f2.w);
      w1[4] = f2bf(f3.x); w1[5] = f2bf(f3.y); w1[6] = f2bf(f3.z); w1[7] = f2bf(f3.w);
    } else {
      w0 = *(const s8v*)(Wrow_b + k0);
      w1 = *(const s8v*)(Wrow_b + k0 + 8);
    }
    __syncthreads();
    *(s8v*)&As[sr][sc] = a0;
    *(s8v*)&As[sr][sc + 8] = a1;
    *(s8v*)&Ws[sr][sc] = w0;
    *(s8v*)&Ws[sr][sc + 8] = w1;
    __syncthreads();
    s8v af[4], bf[4];
#pragma unroll
    for (int m = 0; m < 4; m++) af[m] = *(const s8v*)&As[wm + m * 16 + fr][kg * 8];
#pragma unroll
    for (int n = 0; n < 4; n++) bf[n] = *(const s8v*)&Ws[wn + n * 16 + fr][kg * 8];
#pragma unroll
    for (int m = 0; m < 4; m++)
#pragma unroll
      for (int n = 0; n < 4; n++)
        acc[m][n] = __builtin_amdgcn_mfma_f32_16x16x32_bf16(af[m], bf[n], acc[m][n], 0, 0, 0);
  }
  int rbase = bm + wm + (lane >> 4) * 4;
#pragma unroll
  for (int n = 0; n < 4; n++) {
    int col = bn + wn + n * 16 + (lane & 15);
    if (col >= N) continue;
    float bv = bias ? bias[col] : 0.0f;
#pragma unroll
    for (int m = 0; m < 4; m++) {
#pragma unroll
      for (int r = 0; r < 4; r++) {
        int row = rbase + m * 16 + r;
        float v = acc[m][n][r] + bv;
        if (act == 1) v = 0.5f * v * (1.0f + erff(v * 0.7071067811865475f));
        else if (act == 2) v = tanhf(v);
        if (OUTBF) Cb[(size_t)row * N + col] = f2bf(v);
        else C[(size_t)row * N + col] = v;
      }
    }
  }
}

// ---------------- phase ----------------
__global__ __launch_bounds__(256) void phase_kernel(
    const short* __restrict__ hbf, const float* __restrict__ pw,
    const float* __restrict__ pb, float* __restrict__ phase) {
  int tok = blockIdx.x, t = threadIdx.x;
  int h = t >> 5, ln = t & 31;
  const short* hr = hbf + (size_t)tok * D;
  const s8v* hv = (const s8v*)(hr + ln * 16);
  s8v h0 = hv[0], h1 = hv[1];
  const float4* wv = (const float4*)(pw + (size_t)h * D + ln * 16);
  float4 w0 = wv[0], w1 = wv[1], w2 = wv[2], w3 = wv[3];
  float acc = 0.f;
  acc += bf2f(h0[0]) * w0.x + bf2f(h0[1]) * w0.y + bf2f(h0[2]) * w0.z + bf2f(h0[3]) * w0.w;
  acc += bf2f(h0[4]) * w1.x + bf2f(h0[5]) * w1.y + bf2f(h0[6]) * w1.z + bf2f(h0[7]) * w1.w;
  acc += bf2f(h1[0]) * w2.x + bf2f(h1[1]) * w2.y + bf2f(h1[2]) * w2.z + bf2f(h1[3]) * w2.w;
  acc += bf2f(h1[4]) * w3.x + bf2f(h1[5]) * w3.y + bf2f(h1[6]) * w3.z + bf2f(h1[7]) * w3.w;
  for (int off = 16; off > 0; off >>= 1) acc += __shfl_down(acc, off, 32);
  if (ln == 0) phase[(size_t)tok * NH + h] = acc + pb[h];
}

// ---------------- MFMA flash attention ----------------
// qkv: bf16 [B, L, 3, H, DH]; phase: fp32 [B*L, H]; out: bf16 [B*L, D]
// Block: 256 threads (4 waves), one (b,h), QBLK=64 query rows. KV tiles of 64.
__global__ __launch_bounds__(256) void mha_kernel(
    const short* __restrict__ qkv, const float* __restrict__ phase,
    short* __restrict__ out) {
  __shared__ short sQ[64][72];
  __shared__ short sK[64][72];
  __shared__ short sVt[64][72];   // transposed V with 8-block XOR swizzle
  __shared__ short sP[64][72];
  __shared__ float sPh[Lseq];
  int bh = blockIdx.y;
  int b = bh >> 3, h = bh & 7;
  int q0 = blockIdx.x * 64;
  int tid = threadIdx.x;
  int lane = tid & 63, wid = tid >> 6;
  int fr = lane & 15, kg = lane >> 4;
  int wm = wid * 16;

  // stage phases for this (b,h)
  for (int j = tid; j < Lseq; j += 256) sPh[j] = phase[((size_t)(b * Lseq + j)) * NH + h];
  // stage Q tile: rows q0..q0+63
  for (int idx = tid; idx < 512; idx += 256) {
    int row = idx >> 3, c8 = (idx & 7) * 8;
    *(s8v*)&sQ[row][c8] =
        *(const s8v*)(qkv + (((size_t)(b * Lseq + q0 + row)) * 3 + 0) * D + h * DH + c8);
  }
  __syncthreads();

  float phq[4];
#pragma unroll
  for (int r = 0; r < 4; r++) phq[r] = sPh[q0 + wm + kg * 4 + r];

  float mrow[4] = {-1e30f, -1e30f, -1e30f, -1e30f};
  float lrow[4] = {0.f, 0.f, 0.f, 0.f};
  f32x4 o[4] = {};   // o[df][r] : row = wm+kg*4+r, col = df*16+fr

  for (int kt = 0; kt < Lseq / 64; kt++) {
    int k0 = kt * 64;
    __syncthreads();
    for (int idx = tid; idx < 512; idx += 256) {
      int row = idx >> 3, c8 = (idx & 7) * 8;
      *(s8v*)&sK[row][c8] =
          *(const s8v*)(qkv + (((size_t)(b * Lseq + k0 + row)) * 3 + 1) * D + h * DH + c8);
      s8v v = *(const s8v*)(qkv + (((size_t)(b * Lseq + k0 + row)) * 3 + 2) * D + h * DH + c8);
      int s = idx & 7;  // == (c8+e)>>3 for e<8
      int swcol = (row & 7) | (((row >> 3) ^ s) << 3);
#pragma unroll
      for (int e = 0; e < 8; e++) sVt[c8 + e][swcol] = v[e];
    }
    __syncthreads();

    // S = Q @ K^T for this wave's 16 rows x 64 cols
    s8v qa0 = *(const s8v*)&sQ[wm + fr][kg * 8];
    s8v qa1 = *(const s8v*)&sQ[wm + fr][32 + kg * 8];
    f32x4 sacc[4];
#pragma unroll
    for (int n = 0; n < 4; n++) {
      f32x4 z = {};
      s8v kb0 = *(const s8v*)&sK[n * 16 + fr][kg * 8];
      s8v kb1 = *(const s8v*)&sK[n * 16 + fr][32 + kg * 8];
      z = __builtin_amdgcn_mfma_f32_16x16x32_bf16(qa0, kb0, z, 0, 0, 0);
      z = __builtin_amdgcn_mfma_f32_16x16x32_bf16(qa1, kb1, z, 0, 0, 0);
      sacc[n] = z;
    }
    // scale + phase bias
    float sv[4][4];
#pragma unroll
    for (int n = 0; n < 4; n++) {
      float phk = sPh[k0 + n * 16 + fr];
#pragma unroll
      for (int r = 0; r < 4; r++) {
        float dp = phq[r] - phk;
        sv[n][r] = sacc[n][r] * 0.125f - dp * dp;
      }
    }
    // online softmax (row = (kg, r); 16 lanes per row group share via shfl_xor on lane&15)
    float mnew[4], alpha[4];
#pragma unroll
    for (int r = 0; r < 4; r++) {
      float mx = fmaxf(fmaxf(sv[0][r], sv[1][r]), fmaxf(sv[2][r], sv[3][r]));
#pragma unroll
      for (int off = 1; off < 16; off <<= 1) mx = fmaxf(mx, __shfl_xor(mx, off, 64));
      mnew[r] = fmaxf(mrow[r], mx);
      alpha[r] = __expf(mrow[r] - mnew[r]);
      mrow[r] = mnew[r];
    }
    float rs[4] = {0.f, 0.f, 0.f, 0.f};
#pragma unroll
    for (int n = 0; n < 4; n++) {
#pragma unroll
      for (int r = 0; r < 4; r++) {
        float p = __expf(sv[n][r] - mnew[r]);
        rs[r] += p;
        sP[wm + kg * 4 + r][n * 16 + fr] = f2bf(p);
      }
    }
#pragma unroll
    for (int r = 0; r < 4; r++) {
#pragma unroll
      for (int off = 1; off < 16; off <<= 1) rs[r] += __shfl_xor(rs[r], off, 64);
      lrow[r] = lrow[r] * alpha[r] + rs[r];
    }
#pragma unroll
    for (int df = 0; df < 4; df++) {
      o[df][0] *= alpha[0]; o[df][1] *= alpha[1];
      o[df][2] *= alpha[2]; o[df][3] *= alpha[3];
    }
    // PV: O += P @ V   (A = P rows of this wave, B = Vt rows)
    s8v pa0 = *(const s8v*)&sP[wm + fr][kg * 8];
    s8v pa1 = *(const s8v*)&sP[wm + fr][32 + kg * 8];
#pragma unroll
    for (int df = 0; df < 4; df++) {
      int d = df * 16 + fr;
      int sblk = (d >> 3) & 7;
      s8v vb0 = *(const s8v*)&sVt[d][((0 + kg) ^ sblk) << 3];
      s8v vb1 = *(const s8v*)&sVt[d][((4 + kg) ^ sblk) << 3];
      o[df] = __builtin_amdgcn_mfma_f32_16x16x32_bf16(pa0, vb0, o[df], 0, 0, 0);
      o[df] = __builtin_amdgcn_mfma_f32_16x16x32_bf16(pa1, vb1, o[df], 0, 0, 0);
    }
  }
  // epilogue
  float inv[4];
#pragma unroll
  for (int r = 0; r < 4; r++) inv[r] = 1.0f / lrow[r];
#pragma unroll
  for (int df = 0; df < 4; df++) {
#pragma unroll
    for (int r = 0; r < 4; r++) {
      int row = q0 + wm + kg * 4 + r;
      out[((size_t)(b * Lseq + row)) * D + h * DH + df * 16 + fr] = f2bf(o[df][r] * inv[r]);
    }
  }
}

// ---------------- boundary gate ----------------
__global__ void gate_kernel(const float* __restrict__ tb, const float* __restrict__ w2,
                            const float* __restrict__ b2, float* __restrict__ gate) {
  int tok = blockIdx.x;
  int lane = threadIdx.x;  // 64
  const float* row = tb + (size_t)tok * D;
  float acc = 0.f;
  for (int d = lane; d < D; d += 64) acc += row[d] * w2[d];
  for (int off = 32; off > 0; off >>= 1) acc += __shfl_down(acc, off, 64);
  if (lane == 0) gate[tok] = 1.0f / (1.0f + expf(-(acc + b2[0])));
}

// ---------------- xg = bf16(x * gate) ----------------
__global__ void xg_kernel(const float* __restrict__ x, const float* __restrict__ gate,
                          short* __restrict__ xg) {
  int tok = blockIdx.x, t = threadIdx.x;
  float g = gate[tok];
  float4 v = *(const float4*)(x + (size_t)tok * D + t * 4);
  short4 o = make_short4(f2bf(v.x * g), f2bf(v.y * g), f2bf(v.z * g), f2bf(v.w * g));
  *(short4*)(xg + (size_t)tok * D + t * 4) = o;
}

extern "C" void kernel_launch(void* const* d_in, const int* in_sizes, int n_in,
                              void* d_out, int out_size, void* d_ws, size_t ws_size,
                              hipStream_t stream) {
  const int* ids = (const int*)d_in[0];
  const float* emb = (const float*)d_in[1];
  const float* pos = (const float*)d_in[2];
  const float* rg_w = (const float*)d_in[3];
  const float* rg_b = (const float*)d_in[4];
  const float* qkv_w = (const float*)d_in[5];
  const float* qkv_b = (const float*)d_in[6];
  const float* out_w = (const float*)d_in[7];
  const float* out_b = (const float*)d_in[8];
  const float* ph_w = (const float*)d_in[9];
  const float* ph_b = (const float*)d_in[10];
  const float* ff1_w = (const float*)d_in[11];
  const float* ff1_b = (const float*)d_in[12];
  const float* ff2_w = (const float*)d_in[13];
  const float* ff2_b = (const float*)d_in[14];
  const float* n1_s = (const float*)d_in[15];
  const float* n1_b = (const float*)d_in[16];
  const float* n2_s = (const float*)d_in[17];
  const float* n2_b = (const float*)d_in[18];
  const float* bw1 = (const float*)d_in[19];
  const float* bb1 = (const float*)d_in[20];
  const float* bw2 = (const float*)d_in[21];
  const float* bb2 = (const float*)d_in[22];
  const float* head_w = (const float*)d_in[23];

  char* w = (char*)d_ws;
  float* x      = (float*)(w + 0);           //  8.39 MB
  float* ao     = (float*)(w + 8388608);     //  8.39 MB (also tanh-buf for bnd)
  float* phase  = (float*)(w + 16777216);    //  0.13 MB
  short* h_bf   = (short*)(w + 16908288);    //  4.19 MB
  short* ao_bf  = (short*)(w + 21102592);    //  4.19 MB
  short* x_bf   = (short*)(w + 25296896);    //  4.19 MB
  short* ff_bf  = (short*)(w + 29491200);    // 16.78 MB
  short* xg_bf  = (short*)(w + 46268416);    //  4.19 MB
  short* qkv_bf = (short*)(w + 50462720);    // 12.58 MB
  short* wqkv   = (short*)(w + 63045632);    //  9.44 MB
  short* wout   = (short*)(w + 72482816);    //  3.15 MB
  short* wff1   = (short*)(w + 75628544);    // 12.58 MB
  short* wff2   = (short*)(w + 88211456);    // 12.58 MB
  short* wbnd   = (short*)(w + 100794368);   //  0.52 MB
  short* whead  = (short*)(w + 101318656);   // 30.72 MB
  const size_t WS_FULL = 132038656;

  float* outf   = (float*)d_out;
  float* logits = outf;
  float* gate   = outf + 122880000;
  float* rg_out = outf + 122884096;

  bool fast = ws_size >= WS_FULL;

  if (fast) {
    f2bf_kernel<<<(4718592 / 8 + 255) / 256, 256, 0, stream>>>(qkv_w, wqkv, 4718592);
    f2bf_kernel<<<(1572864 / 8 + 255) / 256, 256, 0, stream>>>(out_w, wout, 1572864);
    f2bf_kernel<<<(6291456 / 8 + 255) / 256, 256, 0, stream>>>(ff1_w, wff1, 6291456);
    f2bf_kernel<<<(6291456 / 8 + 255) / 256, 256, 0, stream>>>(ff2_w, wff2, 6291456);
    f2bf_kernel<<<(262144 / 8 + 255) / 256, 256, 0, stream>>>(bw1, wbnd, 262144);
    f2bf_kernel<<<(15360000 / 8 + 255) / 256, 256, 0, stream>>>(head_w, whead, 15360000);
  }

  embed_kernel<<<BL, 128, 0, stream>>>(ids, emb, pos, x);

  for (int l = 0; l < NL; l++) {
    rg_ln_kernel<<<BL, 256, 0, stream>>>(
        x, rg_w + (size_t)l * 4 * D, rg_b + l * 4, n1_s + l * D, n1_b + l * D,
        h_bf, (l == NL - 1) ? rg_out : nullptr);
    if (fast)
      gemm_kernel<false, true><<<dim3(12, 32), 256, 0, stream>>>(
          h_bf, wqkv + (size_t)l * 1536 * D, qkv_b + l * 1536, nullptr, qkv_bf, BL, 1536, D, 0);
    else
      gemm_kernel<true, true><<<dim3(12, 32), 256, 0, stream>>>(
          h_bf, qkv_w + (size_t)l * 1536 * D, qkv_b + l * 1536, nullptr, qkv_bf, BL, 1536, D, 0);
    phase_kernel<<<BL, 256, 0, stream>>>(h_bf, ph_w + (size_t)l * NH * D, ph_b + l * NH, phase);
    mha_kernel<<<dim3(Lseq / 64, Bsz * NH), 256, 0, stream>>>(qkv_bf, phase, ao_bf);
    if (fast)
      gemm_kernel<false, false><<<dim3(4, 32), 256, 0, stream>>>(
          ao_bf, wout + (size_t)l * D * D, out_b + l * D, ao, nullptr, BL, D, D, 0);
    else
      gemm_kernel<true, false><<<dim3(4, 32), 256, 0, stream>>>(
          ao_bf, out_w + (size_t)l * D * D, out_b + l * D, ao, nullptr, BL, D, D, 0);
    residual_ln_kernel<<<BL, 256, 0, stream>>>(x, ao, n1_s + l * D, n1_b + l * D, x_bf);
    if (fast)
      gemm_kernel<false, true><<<dim3(16, 32), 256, 0, stream>>>(
          x_bf, wff1 + (size_t)l * 2048 * D, ff1_b + l * 2048, nullptr, ff_bf, BL, 2048, D, 1);
    else
      gemm_kernel<true, true><<<dim3(16, 32), 256, 0, stream>>>(
          x_bf, ff1_w + (size_t)l * 2048 * D, ff1_b + l * 2048, nullptr, ff_bf, BL, 2048, D, 1);
    if (fast)
      gemm_kernel<false, false><<<dim3(4, 32), 256, 0, stream>>>(
          ff_bf, wff2 + (size_t)l * D * 2048, ff2_b + l * D, ao, nullptr, BL, D, 2048, 0);
    else
      gemm_kernel<true, false><<<dim3(4, 32), 256, 0, stream>>>(
          ff_bf, ff2_w + (size_t)l * D * 2048, ff2_b + l * D, ao, nullptr, BL, D, 2048, 0);
    residual_ln_kernel<<<BL, 256, 0, stream>>>(x, ao, n2_s + l * D, n2_b + l * D, x_bf);
  }

  if (fast)
    gemm_kernel<false, false><<<dim3(4, 32), 256, 0, stream>>>(
        x_bf, wbnd, bb1, ao, nullptr, BL, D, D, 2);
  else
    gemm_kernel<true, false><<<dim3(4, 32), 256, 0, stream>>>(
        x_bf, bw1, bb1, ao, nullptr, BL, D, D, 2);
  gate_kernel<<<BL, 64, 0, stream>>>(ao, bw2, bb2, gate);
  xg_kernel<<<BL, 128, 0, stream>>>(x, gate, xg_bf);
  if (fast)
    gemm_kernel<false, false><<<dim3(235, 32), 256, 0, stream>>>(
        xg_bf, whead, nullptr, logits, nullptr, BL, Vocab, D, 0);
  else
    gemm_kernel<true, false><<<dim3(235, 32), 256, 0, stream>>>(
        xg_bf, head_w, nullptr, logits, nullptr, BL, Vocab, D, 0);
}